// Round 1
// baseline (152.177 us; speedup 1.0000x reference)
//
#include <hip/hip_runtime.h>
#include <hip/hip_bf16.h>
#include <math.h>

// KAN layer: out = GELU( einsum('bik,ikj->bj', basis, W) + bias ),
//   basis[b,i,k] = x[b,i]^k, B=4096, D=1024, K=5, U=1024.
//
// Round 4: GEMM main loop rebuilt as a counted-vmcnt DMA pipeline (T3/T4):
// 4 LDS buffers x 12 KB (BK=32), prefetch distance 3, ONE fused
// "s_waitcnt vmcnt(6); s_barrier" per K-step -- loads stay in flight across
// barriers instead of the __syncthreads() full vmcnt(0) drain that serially
// exposed L2/L3 latency every iteration at 2 waves/SIMD.
// Operands remain pre-packed in MFMA-unit order (1 KB units: lane l holds
// row l&15, k-octet l>>4) so every global_load_lds is a dense 1 KB burst.

#define B_DIM 4096
#define D_DIM 1024
#define U_DIM 1024
#define KT2 4096            // GEMM K after dropping k=0 plane
#define NKB 128             // 32-wide k-blocks

typedef unsigned short ushort_t;
typedef __attribute__((ext_vector_type(8))) short bf16x8;   // MFMA A/B frag
typedef __attribute__((ext_vector_type(4))) float f32x4;    // MFMA C/D frag

__device__ __forceinline__ ushort_t f2bf(float f) {
  union { float f; unsigned int u; } v;
  v.f = f;
  unsigned int r = v.u + 0x7FFFu + ((v.u >> 16) & 1u);
  return (ushort_t)(r >> 16);
}

__device__ __forceinline__ void load_lds16(const ushort_t* g, ushort_t* l) {
  __builtin_amdgcn_global_load_lds(
      (const __attribute__((address_space(1))) ushort_t*)g,
      (__attribute__((address_space(3))) ushort_t*)l, 16, 0, 0);
}

__device__ __forceinline__ float gelu_exact(float v) {
  return 0.5f * v * (1.0f + erff(v * 0.70710678118654752f));
}

// packed addr (ushorts) of (row, k): ((row>>4)*NKB + (k>>5))*512
//                                     + (((k>>3)&3)*16 + (row&15))*8 + (k&7)

// ---------------- prep 1: x -> A_packed (powers 1..4), direct stores ----------------
// one thread = one 16B chunk = 2 i-values x 4 powers. Wave = one 1 KB unit.
__global__ __launch_bounds__(256) void basis_pack_kernel(
    const float* __restrict__ x, ushort_t* __restrict__ Ap) {
  const int t    = threadIdx.x;
  const int wave = t >> 6;
  const int lane = t & 63;
  const int kblk = blockIdx.x * 4 + wave;     // 0..127
  const int m16  = blockIdx.y;                // 0..255
  const int m    = lane & 15;
  const int ko   = lane >> 4;                 // k-octet 0..3
  const int row  = m16 * 16 + m;
  const int i0   = kblk * 8 + ko * 2;

  const float xa = x[(size_t)row * D_DIM + i0];
  const float xb = x[(size_t)row * D_DIM + i0 + 1];
  const float xa2 = xa * xa, xb2 = xb * xb;
  ushort_t o[8];
  o[0] = f2bf(xa);  o[1] = f2bf(xa2); o[2] = f2bf(xa2 * xa); o[3] = f2bf(xa2 * xa2);
  o[4] = f2bf(xb);  o[5] = f2bf(xb2); o[6] = f2bf(xb2 * xb); o[7] = f2bf(xb2 * xb2);
  *(uint4*)(Ap + ((size_t)m16 * NKB + kblk) * 512 + lane * 8) = *(const uint4*)o;
}

// ---------------- prep 2: W -> B_packed (planes 1..4), direct gather ----------------
__global__ __launch_bounds__(256) void w_pack_kernel(
    const float* __restrict__ W, ushort_t* __restrict__ Bp) {
  const int t    = threadIdx.x;
  const int wave = t >> 6;
  const int lane = t & 63;
  const int kblk = blockIdx.x * 4 + wave;     // 0..127
  const int n16  = blockIdx.y;                // 0..63
  const int jj   = lane & 15;
  const int ko   = lane >> 4;
  const int j    = n16 * 16 + jj;
  const int i0   = kblk * 8 + ko * 2;

  ushort_t o[8];
#pragma unroll
  for (int t2 = 0; t2 < 2; ++t2) {
    const int i = i0 + t2;
#pragma unroll
    for (int e = 0; e < 4; ++e) {
      const int r = i * 5 + e + 1;            // skip k=0 plane
      o[t2 * 4 + e] = f2bf(W[(size_t)r * U_DIM + j]);
    }
  }
  *(uint4*)(Bp + ((size_t)n16 * NKB + kblk) * 512 + lane * 8) = *(const uint4*)o;
}

// ---------------- prep 3: fold k=0 plane into bias ----------------
__global__ __launch_bounds__(256) void fold_part_kernel(
    const float* __restrict__ W, float* __restrict__ part) {
  const int j = blockIdx.x * 256 + threadIdx.x;   // grid.x = 4
  const int g = blockIdx.y;                        // 0..31
  float s = 0.0f;
#pragma unroll 8
  for (int ii = 0; ii < 32; ++ii) {
    const int i = g * 32 + ii;
    s += W[(size_t)(i * 5) * U_DIM + j];
  }
  part[(size_t)g * U_DIM + j] = s;
}

__global__ __launch_bounds__(256) void fold_final_kernel(
    const float* __restrict__ part, const float* __restrict__ bias,
    float* __restrict__ bias2) {
  const int j = blockIdx.x * 256 + threadIdx.x;   // grid.x = 4
  float s = bias[j];
#pragma unroll
  for (int g = 0; g < 32; ++g) s += part[(size_t)g * U_DIM + j];
  bias2[j] = s;
}

// ---------------- main GEMM: 64x128 tile, BK=32, 4-buf counted-vmcnt pipeline ----------------
// buffer layout: unit u = r (r 0..3 = A m16 r, r 4..11 = B n16 r-4).
// 12 KB per buffer, x4 = 48 KB. Prefetch distance 3: stage(it+3) issued at
// iter it; wait vmcnt(6) keeps stages it+1,it+2 (2 x 3 loads/thread) in
// flight across the barrier -- never drain to 0 in the main loop.
__global__ __launch_bounds__(256) void gemm_kernel(
    const ushort_t* __restrict__ Ap, const ushort_t* __restrict__ Bp,
    const float* __restrict__ bias2, float* __restrict__ C) {
  __shared__ ushort_t lds[4][12 * 512];   // 4 x 12 KB

  const int tid  = threadIdx.x;
  const int wave = tid >> 6;
  const int lane = tid & 63;
  const int wm   = wave >> 1;             // 0..1 : 32-row half
  const int wn   = wave & 1;              // 0..1 : 64-col half
  const int m16b = blockIdx.y * 4;        // tile M=64 -> 4 m16 blocks
  const int n16b = blockIdx.x * 8;        // tile N=128 -> 8 n16 blocks

  // staging assignment: s=0..2, unit u = s*4 + wave (dense 1 KB bursts)
  const ushort_t* gsrc[3];
  int ldst[3];
#pragma unroll
  for (int s = 0; s < 3; ++s) {
    const int u = s * 4 + wave;           // 0..11
    const ushort_t* base = (u < 4)
        ? Ap + ((size_t)(m16b + u) * NKB) * 512
        : Bp + ((size_t)(n16b + (u - 4)) * NKB) * 512;
    gsrc[s] = base + lane * 8;
    ldst[s] = u * 512 + lane * 8;
  }

  f32x4 acc[2][4];
  const f32x4 zero = {0.0f, 0.0f, 0.0f, 0.0f};
#pragma unroll
  for (int mf = 0; mf < 2; ++mf)
#pragma unroll
    for (int nf = 0; nf < 4; ++nf) acc[mf][nf] = zero;

#define STAGE(bb, it)                                                   \
  do {                                                                  \
    _Pragma("unroll")                                                   \
    for (int s = 0; s < 3; ++s)                                         \
      load_lds16(gsrc[s] + (size_t)(it) * 512, &lds[bb][ldst[s]]);      \
  } while (0)

#define COMPUTE(bb)                                                     \
  do {                                                                  \
    bf16x8 a[2], b[4];                                                  \
    _Pragma("unroll")                                                   \
    for (int mf = 0; mf < 2; ++mf)                                      \
      a[mf] = *(const bf16x8*)&lds[bb][(wm * 2 + mf) * 512 + lane * 8]; \
    _Pragma("unroll")                                                   \
    for (int nf = 0; nf < 4; ++nf)                                      \
      b[nf] = *(const bf16x8*)&lds[bb][(4 + wn * 4 + nf) * 512 + lane * 8]; \
    _Pragma("unroll")                                                   \
    for (int mf = 0; mf < 2; ++mf)                                      \
      _Pragma("unroll")                                                 \
      for (int nf = 0; nf < 4; ++nf)                                    \
        acc[mf][nf] = __builtin_amdgcn_mfma_f32_16x16x32_bf16(          \
            a[mf], b[nf], acc[mf][nf], 0, 0, 0);                        \
  } while (0)

  STAGE(0, 0);
  STAGE(1, 1);
  STAGE(2, 2);

  // main loop: 128 k-blocks total; iters 0..124 stage it+3, peel the last 3.
  for (int it = 0; it < 125; ++it) {
    // wait only for stage(it) (2 newer stages = 6 loads stay in flight),
    // then one barrier. Fused in one asm so nothing can slip between, and
    // the memory clobber pins LDS reads/DMA issues on the correct side.
    asm volatile("s_waitcnt vmcnt(6)\n\ts_barrier" ::: "memory");
    STAGE((it + 3) & 3, it + 3);
    COMPUTE(it & 3);
  }
  asm volatile("s_waitcnt vmcnt(6)\n\ts_barrier" ::: "memory");
  COMPUTE(1);   // it = 125
  asm volatile("s_waitcnt vmcnt(3)\n\ts_barrier" ::: "memory");
  COMPUTE(2);   // it = 126
  asm volatile("s_waitcnt vmcnt(0)\n\ts_barrier" ::: "memory");
  COMPUTE(3);   // it = 127
#undef STAGE
#undef COMPUTE

  // epilogue: C/D map: col = lane&15, row = (lane>>4)*4 + reg
  const int crow0 = m16b * 16 + wm * 32 + (lane >> 4) * 4;
  const int ccol0 = n16b * 16 + wn * 64 + (lane & 15);
#pragma unroll
  for (int nf = 0; nf < 4; ++nf) {
    const int col = ccol0 + nf * 16;
    const float bv = bias2[col];
#pragma unroll
    for (int mf = 0; mf < 2; ++mf) {
#pragma unroll
      for (int r = 0; r < 4; ++r) {
        const int row = crow0 + mf * 16 + r;
        C[(size_t)row * U_DIM + col] = gelu_exact(acc[mf][nf][r] + bv);
      }
    }
  }
}

// ---------------- fallback (ws too small): fp32, no workspace ----------------
__global__ void fallback_kernel(const float* __restrict__ x, const float* __restrict__ W,
                                const float* __restrict__ bias, float* __restrict__ out) {
  int j  = blockIdx.x * 256 + threadIdx.x;
  int b0 = blockIdx.y * 16;
  float acc[16];
#pragma unroll
  for (int t = 0; t < 16; ++t) acc[t] = 0.0f;
  for (int i = 0; i < D_DIM; ++i) {
    const float* wr = W + (size_t)i * 5 * U_DIM + j;
    float w0 = wr[0 * U_DIM], w1 = wr[1 * U_DIM], w2 = wr[2 * U_DIM];
    float w3 = wr[3 * U_DIM], w4 = wr[4 * U_DIM];
#pragma unroll
    for (int t = 0; t < 16; ++t) {
      float xv = x[(size_t)(b0 + t) * D_DIM + i];
      float x2 = xv * xv;
      acc[t] += w0 + xv * w1 + x2 * w2 + x2 * xv * w3 + x2 * x2 * w4;
    }
  }
  float bv = bias[j];
#pragma unroll
  for (int t = 0; t < 16; ++t)
    out[(size_t)(b0 + t) * U_DIM + j] = gelu_exact(acc[t] + bv);
}

extern "C" void kernel_launch(void* const* d_in, const int* in_sizes, int n_in,
                              void* d_out, int out_size, void* d_ws, size_t ws_size,
                              hipStream_t stream) {
  const float* x    = (const float*)d_in[0];   // (4096, 1024)
  const float* W    = (const float*)d_in[1];   // (1024, 5, 1024), row r = i*5+k
  const float* bias = (const float*)d_in[2];   // (1024,)
  float* out = (float*)d_out;                  // (4096, 1024) fp32

  const size_t szA = (size_t)B_DIM * KT2 * sizeof(ushort_t);   // 33.55 MB
  const size_t szB = (size_t)U_DIM * KT2 * sizeof(ushort_t);   //  8.39 MB
  const size_t szP = (size_t)32 * U_DIM * sizeof(float);       //  128 KB
  const size_t szb = (size_t)U_DIM * sizeof(float);            //    4 KB

  if (ws_size >= szA + szB + szP + szb) {
    ushort_t* Ap   = (ushort_t*)d_ws;
    ushort_t* Bp   = (ushort_t*)((char*)d_ws + szA);
    float*    part = (float*)((char*)d_ws + szA + szB);
    float*    b2   = (float*)((char*)d_ws + szA + szB + szP);
    basis_pack_kernel<<<dim3(NKB / 4, B_DIM / 16), 256, 0, stream>>>(x, Ap);
    w_pack_kernel<<<dim3(NKB / 4, U_DIM / 16), 256, 0, stream>>>(W, Bp);
    fold_part_kernel<<<dim3(U_DIM / 256, 32), 256, 0, stream>>>(W, part);
    fold_final_kernel<<<dim3(U_DIM / 256), 256, 0, stream>>>(part, bias, b2);
    gemm_kernel<<<dim3(U_DIM / 128, B_DIM / 64), 256, 0, stream>>>(Ap, Bp, b2, out);
  } else {
    fallback_kernel<<<dim3(U_DIM / 256, B_DIM / 16), 256, 0, stream>>>(x, W, bias, out);
  }
}